// Round 4
// baseline (688.910 us; speedup 1.0000x reference)
//
#include <hip/hip_runtime.h>

// ---------------------------------------------------------------------------
// Attention (B=8,S=4096,E=2048,D=128), no 1/sqrt(d) scale.
// Split-bf16 (hi+lo) precision on the score chain:
//   q,k = x_hi@W_hi + x_lo@W_hi + x_hi@W_lo   (fp32-grade projections)
//   S   = K_hi.Q_hi + K_lo.Q_hi + K_hi.Q_lo   (fp32-grade scores)
// V / P stay single bf16 (their rounding error lands directly in the output
// at ~0.01 absmax, well under the 0.097 threshold).
//   k1: W f32 -> Wt_hi/Wt_lo bf16 [mat][128][2048]
//   k2: fused QKV: writes Qh,Ql,Kh,Kl row-major + V TRANSPOSED [B][128][4096]
//   k3: flash attention, swapped QK^T (mfma(K,Q)), online softmax, fp32 out.
// ---------------------------------------------------------------------------

#define B_ 8
#define S_ 4096
#define E_ 2048
#define D_ 128

typedef __attribute__((ext_vector_type(8))) short short8;
typedef __attribute__((ext_vector_type(4))) float floatx4;

__device__ __forceinline__ unsigned short f2bf(float f) {
  unsigned u = __builtin_bit_cast(unsigned, f);
  u += 0x7fffu + ((u >> 16) & 1u);   // RNE
  return (unsigned short)(u >> 16);
}
__device__ __forceinline__ float bf2f(unsigned short h) {
  unsigned u = ((unsigned)h) << 16;
  return __builtin_bit_cast(float, u);
}

// ---- kernel 1: transpose + convert + split weights ------------------------
__global__ __launch_bounds__(256)
void wt_kernel(const float* __restrict__ Wq, const float* __restrict__ Wk,
               const float* __restrict__ Wv, unsigned short* __restrict__ Wth,
               unsigned short* __restrict__ Wtl) {
  int bid = blockIdx.x;            // 0..383
  int mat = bid >> 7;
  int n   = bid & 127;
  const float* W = (mat == 0) ? Wq : (mat == 1) ? Wk : Wv;
  unsigned short* oh = Wth + (size_t)mat * (D_ * E_) + (size_t)n * E_;
  unsigned short* ol = Wtl + (size_t)mat * (D_ * E_) + (size_t)n * E_; // mat<2 only
  int k0 = threadIdx.x * 8;
#pragma unroll
  for (int j = 0; j < 8; ++j) {
    float w = W[(size_t)(k0 + j) * D_ + n];
    unsigned short h = f2bf(w);
    oh[k0 + j] = h;
    if (mat < 2) ol[k0 + j] = f2bf(w - bf2f(h));
  }
}

// ---- kernel 2: fused QKV projection (split precision for Q,K) -------------
// grid 256 (M tiles of 128 rows), 512 threads = 8 waves (4M x 2N).
// LDS: Ah/Al[128][72] + Bh[3][128][72] + Bl[2][128][72] = 126 KB (1 block/CU).
__global__ __launch_bounds__(512)
void qkv_kernel(const float* __restrict__ x, const unsigned short* __restrict__ Wth,
                const unsigned short* __restrict__ Wtl,
                const float* __restrict__ bq, const float* __restrict__ bk,
                const float* __restrict__ bv,
                unsigned short* __restrict__ Qh, unsigned short* __restrict__ Ql,
                unsigned short* __restrict__ Kh, unsigned short* __restrict__ Kl,
                unsigned short* __restrict__ VTo) {
  __shared__ unsigned short Ah[128][72];
  __shared__ unsigned short Al[128][72];
  __shared__ unsigned short Bh[3][128][72];
  __shared__ unsigned short Bl[2][128][72];

  const int t    = threadIdx.x;
  const int m0   = blockIdx.x * 128;
  const int wid  = t >> 6, lane = t & 63;
  const int mb   = (wid >> 1) * 32, nb = (wid & 1) * 64;
  const int lr   = lane & 15, lg = lane >> 4;
  const int arow = t >> 2, aseg = t & 3;       // staging map (16 elems each)

  floatx4 zero4 = {0.f, 0.f, 0.f, 0.f};
  floatx4 acc[3][2][4];
#pragma unroll
  for (int mat = 0; mat < 3; ++mat)
#pragma unroll
    for (int mf = 0; mf < 2; ++mf)
#pragma unroll
      for (int nf = 0; nf < 4; ++nf) acc[mat][mf][nf] = zero4;

  for (int kk = 0; kk < E_; kk += 64) {
    __syncthreads();
    { // stage A: x fp32 -> (hi,lo) bf16 LDS
      const float* src = x + (size_t)(m0 + arow) * E_ + kk + aseg * 16;
      float f[16];
      *(float4*)&f[0]  = *(const float4*)(src);
      *(float4*)&f[4]  = *(const float4*)(src + 4);
      *(float4*)&f[8]  = *(const float4*)(src + 8);
      *(float4*)&f[12] = *(const float4*)(src + 12);
      unsigned short th[16], tl[16];
#pragma unroll
      for (int j = 0; j < 16; ++j) {
        unsigned short h = f2bf(f[j]);
        th[j] = h;
        tl[j] = f2bf(f[j] - bf2f(h));
      }
      *(short8*)&Ah[arow][aseg * 16]     = *(short8*)&th[0];
      *(short8*)&Ah[arow][aseg * 16 + 8] = *(short8*)&th[8];
      *(short8*)&Al[arow][aseg * 16]     = *(short8*)&tl[0];
      *(short8*)&Al[arow][aseg * 16 + 8] = *(short8*)&tl[8];
    }
#pragma unroll
    for (int mat = 0; mat < 3; ++mat) { // stage B hi
      const unsigned short* src = Wth + (size_t)mat * (D_ * E_) + (size_t)arow * E_ + kk + aseg * 16;
      *(short8*)&Bh[mat][arow][aseg * 16]     = *(const short8*)(src);
      *(short8*)&Bh[mat][arow][aseg * 16 + 8] = *(const short8*)(src + 8);
    }
#pragma unroll
    for (int mat = 0; mat < 2; ++mat) { // stage B lo (q,k only)
      const unsigned short* src = Wtl + (size_t)mat * (D_ * E_) + (size_t)arow * E_ + kk + aseg * 16;
      *(short8*)&Bl[mat][arow][aseg * 16]     = *(const short8*)(src);
      *(short8*)&Bl[mat][arow][aseg * 16 + 8] = *(const short8*)(src + 8);
    }
    __syncthreads();
#pragma unroll
    for (int ks = 0; ks < 2; ++ks) {
      short8 a0h = *(const short8*)&Ah[mb + lr][ks * 32 + lg * 8];
      short8 a1h = *(const short8*)&Ah[mb + 16 + lr][ks * 32 + lg * 8];
      short8 a0l = *(const short8*)&Al[mb + lr][ks * 32 + lg * 8];
      short8 a1l = *(const short8*)&Al[mb + 16 + lr][ks * 32 + lg * 8];
#pragma unroll
      for (int mat = 0; mat < 2; ++mat) {   // q,k: 3-term split
#pragma unroll
        for (int nf = 0; nf < 4; ++nf) {
          short8 bh = *(const short8*)&Bh[mat][nb + nf * 16 + lr][ks * 32 + lg * 8];
          short8 bl = *(const short8*)&Bl[mat][nb + nf * 16 + lr][ks * 32 + lg * 8];
          acc[mat][0][nf] = __builtin_amdgcn_mfma_f32_16x16x32_bf16(a0h, bh, acc[mat][0][nf], 0, 0, 0);
          acc[mat][0][nf] = __builtin_amdgcn_mfma_f32_16x16x32_bf16(a0l, bh, acc[mat][0][nf], 0, 0, 0);
          acc[mat][0][nf] = __builtin_amdgcn_mfma_f32_16x16x32_bf16(a0h, bl, acc[mat][0][nf], 0, 0, 0);
          acc[mat][1][nf] = __builtin_amdgcn_mfma_f32_16x16x32_bf16(a1h, bh, acc[mat][1][nf], 0, 0, 0);
          acc[mat][1][nf] = __builtin_amdgcn_mfma_f32_16x16x32_bf16(a1l, bh, acc[mat][1][nf], 0, 0, 0);
          acc[mat][1][nf] = __builtin_amdgcn_mfma_f32_16x16x32_bf16(a1h, bl, acc[mat][1][nf], 0, 0, 0);
        }
      }
#pragma unroll
      for (int nf = 0; nf < 4; ++nf) {      // v: single bf16
        short8 bh = *(const short8*)&Bh[2][nb + nf * 16 + lr][ks * 32 + lg * 8];
        acc[2][0][nf] = __builtin_amdgcn_mfma_f32_16x16x32_bf16(a0h, bh, acc[2][0][nf], 0, 0, 0);
        acc[2][1][nf] = __builtin_amdgcn_mfma_f32_16x16x32_bf16(a1h, bh, acc[2][1][nf], 0, 0, 0);
      }
    }
  }

  const float* bias_p[3] = {bq, bk, bv};
#pragma unroll
  for (int mat = 0; mat < 3; ++mat) {
#pragma unroll
    for (int nf = 0; nf < 4; ++nf) {
      int col = nb + nf * 16 + lr;
      float bias = bias_p[mat][col];
#pragma unroll
      for (int mf = 0; mf < 2; ++mf) {
#pragma unroll
        for (int r = 0; r < 4; ++r) {
          int row = m0 + mb + mf * 16 + lg * 4 + r;   // C layout: row=(lg)*4+r
          float val = acc[mat][mf][nf][r] + bias;
          unsigned short h = f2bf(val);
          if (mat == 0) {
            Qh[(size_t)row * D_ + col] = h;
            Ql[(size_t)row * D_ + col] = f2bf(val - bf2f(h));
          } else if (mat == 1) {
            Kh[(size_t)row * D_ + col] = h;
            Kl[(size_t)row * D_ + col] = f2bf(val - bf2f(h));
          } else {
            int b = row >> 12, s = row & 4095;        // V transposed: [B][128][4096]
            VTo[((size_t)b * D_ + col) * S_ + s] = h;
          }
        }
      }
    }
  }
}

// ---- kernel 3: flash attention (split-precision scores) -------------------
// grid 256: batch = bid&7 (XCD affinity), qt = bid>>3. 512 thr = 8 waves.
// LDS: Klh/Kll[64][136] + Vl/Pl[128][72] = 70 KB (2 blocks/CU).
__global__ __launch_bounds__(512)
void attn_kernel(const unsigned short* __restrict__ Qhg, const unsigned short* __restrict__ Qlg,
                 const unsigned short* __restrict__ Khg, const unsigned short* __restrict__ Klg,
                 const unsigned short* __restrict__ VTg, float* __restrict__ out) {
  __shared__ unsigned short Klh[64][136];
  __shared__ unsigned short Kll[64][136];
  __shared__ unsigned short Vl[128][72];
  __shared__ unsigned short Pl[128][72];

  const int t = threadIdx.x;
  const int batch = blockIdx.x & 7, qt = blockIdx.x >> 3;
  const int wid = t >> 6, lane = t & 63;
  const int lr = lane & 15, lg = lane >> 4;
  const int qbase = wid * 16;
  const size_t qrow = (size_t)batch * S_ + qt * 128 + qbase + lr;

  // Q fragments (hi,lo) in registers (B-operand for swapped QK^T)
  short8 qfh[4], qfl[4];
#pragma unroll
  for (int ks = 0; ks < 4; ++ks) {
    qfh[ks] = *(const short8*)(Qhg + qrow * D_ + ks * 32 + lg * 8);
    qfl[ks] = *(const short8*)(Qlg + qrow * D_ + ks * 32 + lg * 8);
  }

  floatx4 zero4 = {0.f, 0.f, 0.f, 0.f};
  floatx4 o[8];
#pragma unroll
  for (int nf = 0; nf < 8; ++nf) o[nf] = zero4;
  float m = -1e30f, l = 0.f;

  const int krow = t >> 3, kseg = t & 7;      // K stage: [64][128]
  const int vd = t >> 2, vseg = t & 3;        // VT stage: [128][64]
  const unsigned short* Khb = Khg + (size_t)batch * S_ * D_;
  const unsigned short* Klb = Klg + (size_t)batch * S_ * D_;
  const unsigned short* Vb  = VTg + (size_t)batch * D_ * S_;

  for (int kv0 = 0; kv0 < S_; kv0 += 64) {
    __syncthreads();
    {
      const unsigned short* srch = Khb + (size_t)(kv0 + krow) * D_ + kseg * 16;
      *(short8*)&Klh[krow][kseg * 16]     = *(const short8*)(srch);
      *(short8*)&Klh[krow][kseg * 16 + 8] = *(const short8*)(srch + 8);
      const unsigned short* srcl = Klb + (size_t)(kv0 + krow) * D_ + kseg * 16;
      *(short8*)&Kll[krow][kseg * 16]     = *(const short8*)(srcl);
      *(short8*)&Kll[krow][kseg * 16 + 8] = *(const short8*)(srcl + 8);
      const unsigned short* vsrc = Vb + (size_t)vd * S_ + kv0 + vseg * 16;
      *(short8*)&Vl[vd][vseg * 16]     = *(const short8*)(vsrc);
      *(short8*)&Vl[vd][vseg * 16 + 8] = *(const short8*)(vsrc + 8);
    }
    __syncthreads();

    // ST[kv][q] = K.Q^T (3-term split): lane holds 16 scores for q=qbase+lr
    floatx4 st[4] = {zero4, zero4, zero4, zero4};
#pragma unroll
    for (int ks = 0; ks < 4; ++ks) {
#pragma unroll
      for (int mf = 0; mf < 4; ++mf) {
        short8 kfh = *(const short8*)&Klh[mf * 16 + lr][ks * 32 + lg * 8];
        short8 kfl = *(const short8*)&Kll[mf * 16 + lr][ks * 32 + lg * 8];
        st[mf] = __builtin_amdgcn_mfma_f32_16x16x32_bf16(kfh, qfh[ks], st[mf], 0, 0, 0);
        st[mf] = __builtin_amdgcn_mfma_f32_16x16x32_bf16(kfl, qfh[ks], st[mf], 0, 0, 0);
        st[mf] = __builtin_amdgcn_mfma_f32_16x16x32_bf16(kfh, qfl[ks], st[mf], 0, 0, 0);
      }
    }

    // online softmax over kv (4 lanes per q: xor 16, 32)
    float tmax = -1e30f;
#pragma unroll
    for (int mf = 0; mf < 4; ++mf)
#pragma unroll
      for (int r = 0; r < 4; ++r) tmax = fmaxf(tmax, st[mf][r]);
    tmax = fmaxf(tmax, __shfl_xor(tmax, 16));
    tmax = fmaxf(tmax, __shfl_xor(tmax, 32));
    float mnew = fmaxf(m, tmax);
    float scale = __expf(m - mnew);
    float tsum = 0.f;
    float p[4][4];
#pragma unroll
    for (int mf = 0; mf < 4; ++mf)
#pragma unroll
      for (int r = 0; r < 4; ++r) {
        p[mf][r] = __expf(st[mf][r] - mnew);
        tsum += p[mf][r];
      }
    tsum += __shfl_xor(tsum, 16);
    tsum += __shfl_xor(tsum, 32);
    l = l * scale + tsum;
    m = mnew;

    // P -> LDS (bf16)
#pragma unroll
    for (int mf = 0; mf < 4; ++mf)
#pragma unroll
      for (int r = 0; r < 4; ++r)
        Pl[qbase + lr][mf * 16 + lg * 4 + r] = f2bf(p[mf][r]);

    // rescale O (O rows live at q = lg*4+r -> fetch scale via shfl)
    float scr[4];
#pragma unroll
    for (int r = 0; r < 4; ++r)
      scr[r] = __shfl(scale, (lane & 48) | (lg * 4 + r));
#pragma unroll
    for (int nf = 0; nf < 8; ++nf)
#pragma unroll
      for (int r = 0; r < 4; ++r) o[nf][r] *= scr[r];

    // PV: O[q][d] += P[q][kv] * V[kv][d]
#pragma unroll
    for (int ks2 = 0; ks2 < 2; ++ks2) {
      short8 pa = *(const short8*)&Pl[qbase + lr][ks2 * 32 + lg * 8];
#pragma unroll
      for (int nf = 0; nf < 8; ++nf) {
        short8 vf = *(const short8*)&Vl[nf * 16 + lr][ks2 * 32 + lg * 8];
        o[nf] = __builtin_amdgcn_mfma_f32_16x16x32_bf16(pa, vf, o[nf], 0, 0, 0);
      }
    }
  }

  float li[4];
#pragma unroll
  for (int r = 0; r < 4; ++r) {
    float lv = __shfl(l, (lane & 48) | (lg * 4 + r));
    li[r] = 1.f / lv;
  }
  const size_t orow0 = (size_t)batch * S_ + qt * 128 + qbase;
#pragma unroll
  for (int nf = 0; nf < 8; ++nf)
#pragma unroll
    for (int r = 0; r < 4; ++r)
      out[(orow0 + lg * 4 + r) * D_ + nf * 16 + lr] = o[nf][r] * li[r];
}

// ---------------------------------------------------------------------------
extern "C" void kernel_launch(void* const* d_in, const int* in_sizes, int n_in,
                              void* d_out, int out_size, void* d_ws, size_t ws_size,
                              hipStream_t stream) {
  const float* x  = (const float*)d_in[0];
  const float* Wq = (const float*)d_in[1];
  const float* bq = (const float*)d_in[2];
  const float* Wk = (const float*)d_in[3];
  const float* bk = (const float*)d_in[4];
  const float* Wv = (const float*)d_in[5];
  const float* bv = (const float*)d_in[6];

  const size_t NQ = (size_t)B_ * S_ * D_;                      // 4.19M elems
  unsigned short* Wth = (unsigned short*)d_ws;                 // 3*128*2048
  unsigned short* Wtl = Wth + (size_t)3 * D_ * E_;             // 2 used (q,k)
  unsigned short* Qhw = Wtl + (size_t)3 * D_ * E_;
  unsigned short* Qlw = Qhw + NQ;
  unsigned short* Khw = Qlw + NQ;
  unsigned short* Klw = Khw + NQ;
  unsigned short* VTw = Klw + NQ;                              // [B][128][4096]

  wt_kernel<<<dim3(384), dim3(256), 0, stream>>>(Wq, Wk, Wv, Wth, Wtl);
  qkv_kernel<<<dim3(256), dim3(512), 0, stream>>>(x, Wth, Wtl, bq, bk, bv,
                                                  Qhw, Qlw, Khw, Klw, VTw);
  attn_kernel<<<dim3(256), dim3(512), 0, stream>>>(Qhw, Qlw, Khw, Klw, VTw,
                                                   (float*)d_out);
}